// Round 18
// baseline (219.993 us; speedup 1.0000x reference)
//
#include <hip/hip_runtime.h>
#include <math.h>

// Problem constants
#define BB 4
#define SS 1024
#define DD 1024
#define HH 16
#define HDIM 64
#define FF 4096
#define MM 4096   // B*S

typedef short bf16x8 __attribute__((ext_vector_type(8)));
typedef short bf16x4 __attribute__((ext_vector_type(4)));
typedef float f32x4  __attribute__((ext_vector_type(4)));

static __device__ __forceinline__ short f2bf(float f){
  unsigned u = __float_as_uint(f);
  u += 0x7FFFu + ((u >> 16) & 1u);   // RNE
  return (short)(u >> 16);
}
static __device__ __forceinline__ float b2f(short s){
  return __uint_as_float(((unsigned)(unsigned short)s) << 16);
}

// fast erf (Abramowitz-Stegun 7.1.26, |abs err| <= 1.5e-7)
static __device__ __forceinline__ float erf_fast(float x){
  float ax = fabsf(x);
  float t  = __builtin_amdgcn_rcpf(1.0f + 0.3275911f * ax);
  float p  = t * (0.254829592f + t * (-0.284496736f + t * (1.421413741f +
             t * (-1.453152027f + t * 1.061405429f))));
  float e  = 1.0f - p * __expf(-ax * ax);
  return copysignf(e, x);
}

// async global->LDS, 16B per lane, LDS dest = base + lane*16 (wave-uniform base)
static __device__ __forceinline__ void gl_lds16(const short* g, short* l){
  __builtin_amdgcn_global_load_lds((const __attribute__((address_space(1))) unsigned int*)g,
                                   (__attribute__((address_space(3))) unsigned int*)l,
                                   16, 0, 0);
}

#define MFMA_BF16 __builtin_amdgcn_mfma_f32_16x16x32_bf16

// ---------------- merged weight f32 -> bf16 transpose (all 6 weights, 1 launch) ----------------
__global__ __launch_bounds__(256) void trans_all_kernel(
    const float* __restrict__ wq, const float* __restrict__ wk,
    const float* __restrict__ wv, const float* __restrict__ wo,
    const float* __restrict__ w1, const float* __restrict__ w2,
    short* __restrict__ wqkvt, short* __restrict__ wot,
    short* __restrict__ w1t,   short* __restrict__ w2t){
  __shared__ float t[32][33];
  int idx = blockIdx.x;
  const float* src; short* dst; int R, C, cx, ry;
  if (idx < 4096){
    int wsel = idx >> 10, tt = idx & 1023;
    cx = tt & 31; ry = tt >> 5; R = 1024; C = 1024;
    src = (wsel == 0) ? wq : (wsel == 1) ? wk : (wsel == 2) ? wv : wo;
    dst = (wsel == 3) ? wot : wqkvt + (size_t)wsel * 1024 * 1024;
  } else if (idx < 8192){
    int tt = idx - 4096; cx = tt & 127; ry = tt >> 7; R = 1024; C = 4096;
    src = w1; dst = w1t;
  } else {
    int tt = idx - 8192; cx = tt & 31; ry = tt >> 5; R = 4096; C = 1024;
    src = w2; dst = w2t;
  }
  int c0 = cx * 32, r0 = ry * 32;
  int tx = threadIdx.x, ty = threadIdx.y;  // (32,8)
#pragma unroll
  for (int i = 0; i < 32; i += 8)
    t[ty + i][tx] = src[(size_t)(r0 + ty + i) * C + (c0 + tx)];
  __syncthreads();
#pragma unroll
  for (int i = 0; i < 32; i += 8)
    dst[(size_t)(c0 + ty + i) * R + (r0 + tx)] = f2bf(t[tx][ty + i]);
}

__global__ __launch_bounds__(256) void concat_bias_kernel(const float* __restrict__ a,
                                                          const float* __restrict__ b,
                                                          const float* __restrict__ c,
                                                          float* __restrict__ dst){
  int t = blockIdx.x * 256 + threadIdx.x;   // 3072
  float v = (t < 1024) ? a[t] : (t < 2048 ? b[t - 1024] : c[t - 2048]);
  dst[t] = v;
}

// ---------------- embedding + sinusoidal PE (bf16 out only) ----------------
__global__ __launch_bounds__(256) void embed_kernel(const int* __restrict__ inputs,
                                                    const float* __restrict__ wte,
                                                    short* __restrict__ xb){
  int idx4 = blockIdx.x * 256 + threadIdx.x;
  int row = idx4 >> 8;
  int d   = (idx4 & 255) * 4;
  int s   = row & (SS - 1);
  int tok = inputs[row];
  float4 w = *(const float4*)&wte[(size_t)tok * DD + d];
  const float cdiv = -9.210340371976184f / 512.0f;
  int i0 = d >> 1;
  float ang0 = (float)s * expf((float)i0 * cdiv);
  float ang1 = (float)s * expf((float)(i0 + 1) * cdiv);
  float x0 = w.x + sinf(ang0);
  float x1 = w.y + cosf(ang0);
  float x2 = w.z + sinf(ang1);
  float x3 = w.w + cosf(ang1);
  bf16x4 sb; sb[0]=f2bf(x0); sb[1]=f2bf(x1); sb[2]=f2bf(x2); sb[3]=f2bf(x3);
  *(bf16x4*)&xb[(size_t)row * DD + d] = sb;
}

// ---------------- 256x256 MFMA GEMM (round-14 config) — QKV only ----------------
template<int MODE, bool GELU, bool ADDBIAS>
__global__ __launch_bounds__(512, 2) void gemm256_kernel(const short* __restrict__ A,
    const short* __restrict__ Bt, const float* __restrict__ bias,
    short* __restrict__ o0, short* __restrict__ o1,
    short* __restrict__ o2, short* __restrict__ o3,
    short* __restrict__ qo, short* __restrict__ ko, short* __restrict__ vto,
    int M, int N, int K, int Kc){
  __shared__ __align__(16) short lds[8 * 8192];   // 128KB
  int tid = threadIdx.x;
  int lid = blockIdx.y * gridDim.x + blockIdx.x;
  int cpx = (gridDim.x * gridDim.y) >> 3;
  int swz = (lid & 7) * cpx + (lid >> 3);
  int n0 = (swz % gridDim.x) * 256;
  int m0 = (swz / gridDim.x) * 256;
  int bz = blockIdx.z;
  int kbeg = bz * Kc;
  int w = tid >> 6, lane = tid & 63, lr = lane & 15, lg = lane >> 4;
  int wm = w >> 2, wn = w & 3;          // 2 (M) x 4 (N) waves
  f32x4 acc[8][4] = {};

  int sr = lane >> 3;
  int sg = (lane & 7) ^ sr;
  auto STAGE_HALF = [&](int buf, int typ, int half, int kt){
    const short* s0 = (typ ? Bt : A) + (size_t)kbeg + sg * 8;
    int rb = (typ ? n0 : m0) + half * 128 + w * 8 + sr;
#pragma unroll
    for (int j = 0; j < 2; j++)
      gl_lds16(s0 + (size_t)(rb + j * 64) * K + kt * 64,
               &lds[(((buf << 2) | (typ << 1) | half) << 13) + (j << 12) + (w << 9)]);
  };

  int nt = Kc >> 6;
  STAGE_HALF(0, 0, 0, 0); STAGE_HALF(0, 0, 1, 0);
  STAGE_HALF(0, 1, 0, 0); STAGE_HALF(0, 1, 1, 0);
  STAGE_HALF(1, 0, 0, 1); STAGE_HALF(1, 0, 1, 1);
  STAGE_HALF(1, 1, 0, 1); STAGE_HALF(1, 1, 1, 1);
  asm volatile("s_waitcnt vmcnt(8)" ::: "memory");
  __builtin_amdgcn_s_barrier();

  int lr64 = lr * 64;
  int ck0 = ((lg     ) ^ (lr & 7)) * 8;
  int ck1 = ((lg + 4 ) ^ (lr & 7)) * 8;
  int brow = (wn & 1) << 12;

  bf16x8 Alo[4][2], Ahi[4][2], Blo[2][2], Bhi[2][2];

#define ABASE(b) ((((b) << 2) | wm) << 13) + lr64
#define BBASE(b) ((((b) << 2) | 2 | (wn >> 1)) << 13) + brow + lr64
#define RD_ALO(b) { int ab_ = ABASE(b); _Pragma("unroll") for (int fi_ = 0; fi_ < 4; fi_++){ \
    Alo[fi_][0] = *(const bf16x8*)&lds[ab_ + fi_ * 1024 + ck0]; \
    Alo[fi_][1] = *(const bf16x8*)&lds[ab_ + fi_ * 1024 + ck1]; } }
#define RD_AHI(b) { int ab_ = ABASE(b); _Pragma("unroll") for (int fi_ = 0; fi_ < 4; fi_++){ \
    Ahi[fi_][0] = *(const bf16x8*)&lds[ab_ + (fi_ + 4) * 1024 + ck0]; \
    Ahi[fi_][1] = *(const bf16x8*)&lds[ab_ + (fi_ + 4) * 1024 + ck1]; } }
#define RD_BLO(b) { int bb_ = BBASE(b); _Pragma("unroll") for (int ni_ = 0; ni_ < 2; ni_++){ \
    Blo[ni_][0] = *(const bf16x8*)&lds[bb_ + ni_ * 1024 + ck0]; \
    Blo[ni_][1] = *(const bf16x8*)&lds[bb_ + ni_ * 1024 + ck1]; } }
#define RD_BHI(b) { int bb_ = BBASE(b); _Pragma("unroll") for (int ni_ = 0; ni_ < 2; ni_++){ \
    Bhi[ni_][0] = *(const bf16x8*)&lds[bb_ + (ni_ + 2) * 1024 + ck0]; \
    Bhi[ni_][1] = *(const bf16x8*)&lds[bb_ + (ni_ + 2) * 1024 + ck1]; } }
#define QUAD(MB, NB, AF, BF) \
    __builtin_amdgcn_s_setprio(1); \
    _Pragma("unroll") for (int mi_ = 0; mi_ < 4; mi_++) \
      _Pragma("unroll") for (int ni_ = 0; ni_ < 2; ni_++){ \
        acc[mi_ + MB][ni_ + NB] = MFMA_BF16(AF[mi_][0], BF[ni_][0], acc[mi_ + MB][ni_ + NB], 0, 0, 0); \
        acc[mi_ + MB][ni_ + NB] = MFMA_BF16(AF[mi_][1], BF[ni_][1], acc[mi_ + MB][ni_ + NB], 0, 0, 0); } \
    __builtin_amdgcn_s_setprio(0);

  RD_ALO(0); RD_BLO(0);

  for (int t = 0; t < nt; t++){
    int b = t & 1, bn = b ^ 1;
    RD_AHI(b);
    asm volatile("s_waitcnt lgkmcnt(8)" ::: "memory");
    __builtin_amdgcn_sched_barrier(0);
    QUAD(0, 0, Alo, Blo);
    __builtin_amdgcn_s_barrier();
    RD_BHI(b);
    if (t + 2 < nt){ STAGE_HALF(b, 0, 0, t + 2); STAGE_HALF(b, 0, 1, t + 2); }
    asm volatile("s_waitcnt lgkmcnt(4)" ::: "memory");
    __builtin_amdgcn_sched_barrier(0);
    QUAD(4, 0, Ahi, Blo);
    __builtin_amdgcn_s_barrier();
    if (t + 2 < nt) asm volatile("s_waitcnt vmcnt(4)" ::: "memory");
    else            asm volatile("s_waitcnt vmcnt(0)" ::: "memory");
    if (t + 2 < nt){ STAGE_HALF(b, 1, 0, t + 2); STAGE_HALF(b, 1, 1, t + 2); }
    asm volatile("s_waitcnt lgkmcnt(0)" ::: "memory");
    __builtin_amdgcn_sched_barrier(0);
    QUAD(4, 2, Ahi, Bhi);
    __builtin_amdgcn_s_barrier();
    QUAD(0, 2, Alo, Bhi);
    __builtin_amdgcn_sched_barrier(0);
    if (t + 1 < nt){ RD_ALO(bn); RD_BLO(bn); }
    __builtin_amdgcn_s_barrier();
  }
#undef QUAD
#undef RD_BHI
#undef RD_BLO
#undef RD_AHI
#undef RD_ALO
#undef BBASE
#undef ABASE

  short* slab = (MODE == 1) ? ((bz == 0) ? o0 : (bz == 1) ? o1 : (bz == 2) ? o2 : o3) : o0;
  bool addb = ADDBIAS && (MODE != 1 || bz == 0);
#pragma unroll
  for (int mi = 0; mi < 8; mi++){
#pragma unroll
    for (int ni = 0; ni < 4; ni++){
      int ng = n0 + wn * 64 + ni * 16 + lr;
      float bv = addb ? bias[ng] : 0.0f;
      int mg0 = m0 + wm * 128 + mi * 16 + 4 * lg;
      if (MODE == 2){
        int sel = n0 >> 10;
        if (sel == 2){
          int d = ng & 1023; int hh = d >> 6, nn = d & 63;
          int bI = mg0 >> 10, sI = mg0 & 1023;
          bf16x4 pk;
#pragma unroll
          for (int r = 0; r < 4; r++) pk[r] = f2bf(acc[mi][ni][r] + bv);
          *(bf16x4*)&vto[(((size_t)(bI * HH + hh)) * HDIM + nn) * SS + sI] = pk;
        } else {
          short* dst = (sel == 0) ? qo : ko;
          float qscl = (sel == 0) ? 0.125f : 1.0f;
#pragma unroll
          for (int r = 0; r < 4; r++)
            dst[(size_t)(mg0 + r) * DD + (ng & 1023)] = f2bf((acc[mi][ni][r] + bv) * qscl);
        }
      } else {
#pragma unroll
        for (int r = 0; r < 4; r++){
          float v = acc[mi][ni][r] + bv;
          if (GELU) v = 0.5f * v * (1.0f + erf_fast(v * 0.70710678118654752f));
          slab[(size_t)(mg0 + r) * N + ng] = f2bf(v);
        }
      }
    }
  }
}

// ---------------- 128x256 MFMA GEMM, 8 waves, BK=32, 48KB LDS, 2 blocks/CU target ----------------
// acc[4][4]=64 regs -> total VGPR ~110-130; TLP (2nd block) covers the 2-phase drain (m97/m114).
// Swizzle (32-col rows): physical chunk = logical ^ ((row>>1)&3) -> 2-way bank aliasing (free).
// Stage source chunk: (lane&3)^((lane>>3)&3). MODE 0: bf16 out (opt GELU); 1: split-K partial.
template<int MODE, bool GELU, bool ADDBIAS>
__global__ __launch_bounds__(512) void gemmw_kernel(const short* __restrict__ A,
    const short* __restrict__ Bt, const float* __restrict__ bias,
    short* __restrict__ o0, short* __restrict__ o1,
    short* __restrict__ o2, short* __restrict__ o3,
    int M, int N, int K, int Kc){
  __shared__ __align__(16) short lds[2][12288];   // 48KB: A[128x32] + B[256x32] per buf
  int tid = threadIdx.x;
  int lid = blockIdx.y * gridDim.x + blockIdx.x;
  int cpx = (gridDim.x * gridDim.y) >> 3;
  int swz = (lid & 7) * cpx + (lid >> 3);
  int n0 = (swz % gridDim.x) * 256;
  int m0 = (swz / gridDim.x) * 128;
  int bz = blockIdx.z;
  int kbeg = bz * Kc;
  int w = tid >> 6, lane = tid & 63, lr = lane & 15, lg = lane >> 4;
  int wm = w >> 2, wn = w & 3;          // 2 (M) x 4 (N) waves; each wave 64x64 out
  f32x4 acc[4][4] = {};

  // staging: lane covers row w*16 + (lane>>2), physical chunk lane&3 <- global chunk sg
  int sr = lane >> 2;
  int sg = (lane & 3) ^ ((lane >> 3) & 3);
  const short* Arow = A  + (size_t)(m0 + w * 16 + sr) * K + kbeg + sg * 8;
  const short* Brow = Bt + (size_t)(n0 + w * 16 + sr) * K + kbeg + sg * 8;

  auto STAGE = [&](int buf, int kt){
    int k0 = kt * 32;
    gl_lds16(Arow + k0, &lds[buf][w * 512]);                                   // A rows w*16..+15
#pragma unroll
    for (int j = 0; j < 2; j++)                                                // B rows j*128+w*16..+15
      gl_lds16(Brow + (size_t)(j * 128) * K + k0, &lds[buf][4096 + j * 4096 + w * 512]);
  };

  int nst = Kc >> 5;
  STAGE(0, 0);
  asm volatile("s_waitcnt vmcnt(0)" ::: "memory");
  __builtin_amdgcn_s_barrier();

  int cxor = ((lr >> 1) & 3) * 8;   // read-side swizzle (chunk XOR), in shorts

  for (int it = 0; it < nst; it++){
    int cur = it & 1;
    if (it + 1 < nst) STAGE(cur ^ 1, it + 1);   // overlaps compute; lands by bottom vmcnt

    bf16x8 af[4], bfr[4];
#pragma unroll
    for (int mi = 0; mi < 4; mi++){
      int row = wm * 64 + mi * 16 + lr;
      af[mi] = *(const bf16x8*)&lds[cur][row * 32 + ((lg * 8) ^ cxor)];
    }
#pragma unroll
    for (int ni = 0; ni < 4; ni++){
      int row = wn * 64 + ni * 16 + lr;
      bfr[ni] = *(const bf16x8*)&lds[cur][4096 + row * 32 + ((lg * 8) ^ cxor)];
    }
    __builtin_amdgcn_s_setprio(1);
#pragma unroll
    for (int mi = 0; mi < 4; mi++)
#pragma unroll
      for (int ni = 0; ni < 4; ni++)
        acc[mi][ni] = MFMA_BF16(af[mi], bfr[ni], acc[mi][ni], 0, 0, 0);
    __builtin_amdgcn_s_setprio(0);
    asm volatile("s_waitcnt vmcnt(0) lgkmcnt(0)" ::: "memory");
    __builtin_amdgcn_s_barrier();
  }

  short* slab = (MODE == 1) ? ((bz == 0) ? o0 : (bz == 1) ? o1 : (bz == 2) ? o2 : o3) : o0;
  bool addb = ADDBIAS && (MODE != 1 || bz == 0);
#pragma unroll
  for (int mi = 0; mi < 4; mi++){
#pragma unroll
    for (int ni = 0; ni < 4; ni++){
      int ng = n0 + wn * 64 + ni * 16 + lr;
      float bv = addb ? bias[ng] : 0.0f;
      int mg0 = m0 + wm * 64 + mi * 16 + 4 * lg;
#pragma unroll
      for (int r = 0; r < 4; r++){
        float v = acc[mi][ni][r] + bv;
        if (GELU) v = 0.5f * v * (1.0f + erf_fast(v * 0.70710678118654752f));
        slab[(size_t)(mg0 + r) * N + ng] = f2bf(v);
      }
    }
  }
}

// ---------------- causal flash attention v5 (round-14 version, unchanged) ----------------
__global__ __launch_bounds__(256) void attn_kernel(const short* __restrict__ qb,
                                                   const short* __restrict__ kb,
                                                   const short* __restrict__ vtb,
                                                   short* __restrict__ ctxb){
  __shared__ __align__(16) short k_lds[2][64 * 64];
  __shared__ __align__(16) short v_lds[2][64 * 64];
  __shared__ __align__(16) short p_lds[4][2][16 * 72];
  int qp = blockIdx.x, h = blockIdx.y, b = blockIdx.z;
  int Tlo = qp, Thi = 15 - qp;
  int tid = threadIdx.x, w = tid >> 6, lane = tid & 63, lr = lane & 15, lg = lane >> 4;

  const short* kp0 = kb  + (size_t)b * SS * DD + h * HDIM;
  const short* vt0 = vtb + (size_t)(b * HH + h) * HDIM * SS;

  bf16x8 qf0[2], qf1[2];
#pragma unroll
  for (int ti = 0; ti < 2; ti++){
    int T = ti ? Thi : Tlo;
    const short* qp_ = qb + ((size_t)(b * SS + T * 64 + w * 16 + lr) * DD + h * HDIM);
    qf0[ti] = *(const bf16x8*)&qp_[lg * 8];
    qf1[ti] = *(const bf16x8*)&qp_[32 + lg * 8];
  }

  bf16x8 ones;
#pragma unroll
  for (int j = 0; j < 8; j++) ones[j] = (short)0x3F80;

  float m[2][4], l[2][4];
  f32x4 acc[2][4] = {};
#pragma unroll
  for (int ti = 0; ti < 2; ti++)
#pragma unroll
    for (int r = 0; r < 4; r++){ m[ti][r] = -1e30f; l[ti][r] = 0.0f; }

  int srow8 = lane >> 3;
  int sjs   = (lane & 7) ^ srow8;
  auto STAGE = [&](int buf, int kt){
#pragma unroll
    for (int i = 0; i < 2; i++){
      int rb  = (w + 4 * i) * 8;
      int row = rb + srow8;
      gl_lds16(kp0 + (size_t)(kt * 64 + row) * DD + sjs * 8, &k_lds[buf][rb * 64]);
      gl_lds16(vt0 + (size_t)row * SS + kt * 64 + sjs * 8,   &v_lds[buf][rb * 64]);
    }
  };

  int cur = 0;
  STAGE(0, 0);
  asm volatile("s_waitcnt vmcnt(0)" ::: "memory");
  __syncthreads();

  bf16x8 pf0[2], pf1[2];
  for (int kt = 0; kt <= Thi; kt++){
    if (kt < Thi) STAGE(cur ^ 1, kt + 1);

    bf16x8 kf0[4], kf1[4];
#pragma unroll
    for (int sub = 0; sub < 4; sub++){
      int r = sub * 16 + lr;
      kf0[sub] = *(const bf16x8*)&k_lds[cur][r * 64 + ((lg     ^ (r & 7)) * 8)];
      kf1[sub] = *(const bf16x8*)&k_lds[cur][r * 64 + (((lg+4) ^ (r & 7)) * 8)];
    }

#pragma unroll
    for (int ti = 0; ti < 2; ti++){
      int T = ti ? Thi : Tlo;
      if (kt > T) continue;
      f32x4 sc4[4];
      __builtin_amdgcn_s_setprio(1);
#pragma unroll
      for (int sub = 0; sub < 4; sub++){
        f32x4 t = {};
        t = MFMA_BF16(qf0[ti], kf0[sub], t, 0, 0, 0);
        t = MFMA_BF16(qf1[ti], kf1[sub], t, 0, 0, 0);
        sc4[sub] = t;
      }
      __builtin_amdgcn_s_setprio(0);
      if (kt == T){
#pragma unroll
        for (int sub = 0; sub < 4; sub++)
#pragma unroll
          for (int r = 0; r < 4; r++)
            if (16 * sub + lr > 16 * w + 4 * lg + r) sc4[sub][r] = -1e30f;
      }

      float pm[4];
#pragma unroll
      for (int r = 0; r < 4; r++)
        pm[r] = fmaxf(fmaxf(sc4[0][r], sc4[1][r]), fmaxf(sc4[2][r], sc4[3][r]));
#pragma unroll
      for (int off = 1; off < 16; off <<= 1)
#pragma unroll
        for (int r = 0; r < 4; r++) pm[r] = fmaxf(pm[r], __shfl_xor(pm[r], off));

      float dmax = fmaxf(fmaxf(pm[0] - m[ti][0], pm[1] - m[ti][1]),
                         fmaxf(pm[2] - m[ti][2], pm[3] - m[ti][3]));
      if (!__all(dmax <= 8.0f)){
        float scl[4];
#pragma unroll
        for (int r = 0; r < 4; r++){
          float mn = fmaxf(m[ti][r], pm[r]);
          scl[r] = __expf(m[ti][r] - mn);
          m[ti][r] = mn;
          l[ti][r] *= scl[r];
        }
#pragma unroll
        for (int nb = 0; nb < 4; nb++)
#pragma unroll
          for (int r = 0; r < 4; r++) acc[ti][nb][r] *= scl[r];
      }

      short* pw = &p_lds[w][ti][0];
#pragma unroll
      for (int sub = 0; sub < 4; sub++)
#pragma unroll
        for (int r = 0; r < 4; r++)
          pw[(4 * lg + r) * 72 + sub * 16 + lr] = f2bf(__expf(sc4[sub][r] - m[ti][r]));
      pf0[ti] = *(const bf16x8*)&pw[lr * 72 + lg * 8];
      pf1[ti] = *(const bf16x8*)&pw[lr * 72 + 32 + lg * 8];
    }

    bf16x8 vf0[4], vf1[4];
#pragma unroll
    for (int nb = 0; nb < 4; nb++){
      int r = nb * 16 + lr;
      vf0[nb] = *(const bf16x8*)&v_lds[cur][r * 64 + ((lg     ^ (r & 7)) * 8)];
      vf1[nb] = *(const bf16x8*)&v_lds[cur][r * 64 + (((lg+4) ^ (r & 7)) * 8)];
    }

#pragma unroll
    for (int ti = 0; ti < 2; ti++){
      int T = ti ? Thi : Tlo;
      if (kt > T) continue;
      f32x4 rsum = {};
      __builtin_amdgcn_s_setprio(1);
      rsum = MFMA_BF16(pf0[ti], ones, rsum, 0, 0, 0);
      rsum = MFMA_BF16(pf1[ti], ones, rsum, 0, 0, 0);
#pragma unroll
      for (int nb = 0; nb < 4; nb++){
        acc[ti][nb] = MFMA_BF16(pf0[ti], vf0[nb], acc[ti][nb], 0, 0, 0);
        acc[ti][nb] = MFMA_BF16(pf1[ti], vf1[nb], acc[ti][nb], 0, 0, 0);
      }
      __builtin_amdgcn_s_setprio(0);
#pragma unroll
      for (int r = 0; r < 4; r++) l[ti][r] += rsum[r];
    }

    asm volatile("s_waitcnt vmcnt(0)" ::: "memory");
    __syncthreads();
    cur ^= 1;
  }

#pragma unroll
  for (int ti = 0; ti < 2; ti++){
    int T = ti ? Thi : Tlo;
#pragma unroll
    for (int r = 0; r < 4; r++){
      float inv = 1.0f / l[ti][r];
      int row = T * 64 + w * 16 + 4 * lg + r;
#pragma unroll
      for (int nb = 0; nb < 4; nb++)
        ctxb[(size_t)(b * SS + row) * DD + h * HDIM + nb * 16 + lr] = f2bf(acc[ti][nb][r] * inv);
    }
  }
}

// ---------------- LayerNorm( bf16 residual + sum of NPART bf16 partial slabs ) ----------------
template<int NPART, bool WF32, bool LOSS>
__global__ __launch_bounds__(256) void ln_kernel(const short* __restrict__ p0,
                                                 const short* __restrict__ p1,
                                                 const short* __restrict__ p2,
                                                 const short* __restrict__ p3,
                                                 const short* __restrict__ resb,
                                                 const float* __restrict__ g,
                                                 const float* __restrict__ be,
                                                 float* __restrict__ of,
                                                 short* __restrict__ ob,
                                                 const int* __restrict__ tgt,
                                                 float* __restrict__ lrow){
  int row = blockIdx.x, tid = threadIdx.x;
  size_t base = (size_t)row * DD + tid * 4;
  bf16x4 rv = *(const bf16x4*)&resb[base];
  float x0 = b2f(rv[0]), x1 = b2f(rv[1]), x2 = b2f(rv[2]), x3 = b2f(rv[3]);
  const short* ps[4] = {p0, p1, p2, p3};
#pragma unroll
  for (int p = 0; p < NPART; p++){
    bf16x4 pv = *(const bf16x4*)&ps[p][base];
    x0 += b2f(pv[0]); x1 += b2f(pv[1]); x2 += b2f(pv[2]); x3 += b2f(pv[3]);
  }
  float s = x0 + x1 + x2 + x3;
  float q = x0 * x0 + x1 * x1 + x2 * x2 + x3 * x3;
#pragma unroll
  for (int off = 32; off; off >>= 1){ s += __shfl_xor(s, off); q += __shfl_xor(q, off); }
  __shared__ float red[9];
  if ((tid & 63) == 0){ red[tid >> 6] = s; red[4 + (tid >> 6)] = q; }
  __syncthreads();
  s = red[0] + red[1] + red[2] + red[3];
  q = red[4] + red[5] + red[6] + red[7];
  float mean = s * (1.0f / DD);
  float var  = q * (1.0f / DD) - mean * mean;
  float rstd = rsqrtf(var + 1e-5f);
  float4 gv  = *(const float4*)&g[tid * 4];
  float4 bev = *(const float4*)&be[tid * 4];
  float y0 = (x0 - mean) * rstd * gv.x + bev.x;
  float y1 = (x1 - mean) * rstd * gv.y + bev.y;
  float y2 = (x2 - mean) * rstd * gv.z + bev.z;
  float y3 = (x3 - mean) * rstd * gv.w + bev.w;
  if (WF32){
    *(float4*)&of[base] = make_float4(y0, y1, y2, y3);
  } else {
    bf16x4 sb; sb[0]=f2bf(y0); sb[1]=f2bf(y1); sb[2]=f2bf(y2); sb[3]=f2bf(y3);
    *(bf16x4*)&ob[base] = sb;
  }
  if (LOSS){
    __syncthreads();
    float mx = fmaxf(fmaxf(y0, y1), fmaxf(y2, y3));
#pragma unroll
    for (int off = 32; off; off >>= 1) mx = fmaxf(mx, __shfl_xor(mx, off));
    if ((tid & 63) == 0) red[tid >> 6] = mx;
    int t = tgt[row];
    if (tid == (t >> 2))
      red[8] = ((t & 3) == 0) ? y0 : ((t & 3) == 1) ? y1 : ((t & 3) == 2) ? y2 : y3;
    __syncthreads();
    mx = fmaxf(fmaxf(red[0], red[1]), fmaxf(red[2], red[3]));
    float se = __expf(y0 - mx) + __expf(y1 - mx) + __expf(y2 - mx) + __expf(y3 - mx);
#pragma unroll
    for (int off = 32; off; off >>= 1) se += __shfl_xor(se, off);
    if ((tid & 63) == 0) red[4 + (tid >> 6)] = se;
    __syncthreads();
    if (tid == 0){
      float tot = red[4] + red[5] + red[6] + red[7];
      lrow[row] = mx + logf(tot) - red[8];
    }
  }
}

__global__ __launch_bounds__(256) void loss_reduce_kernel(const float* __restrict__ pr,
                                                          float* __restrict__ outp){
  int tid = threadIdx.x;
  float s = 0.0f;
  for (int i = tid; i < MM; i += 256) s += pr[i];
#pragma unroll
  for (int off = 32; off; off >>= 1) s += __shfl_xor(s, off);
  __shared__ float red[4];
  if ((tid & 63) == 0) red[tid >> 6] = s;
  __syncthreads();
  if (tid == 0) outp[0] = (red[0] + red[1] + red[2] + red[3]) * (1.0f / MM);
}

// ---------------- launch ----------------
extern "C" void kernel_launch(void* const* d_in, const int* in_sizes, int n_in,
                              void* d_out, int out_size, void* d_ws, size_t ws_size,
                              hipStream_t stream){
  const int*   inputs  = (const int*)  d_in[0];
  const int*   targets = (const int*)  d_in[1];
  const float* wte     = (const float*)d_in[2];
  const float* wq      = (const float*)d_in[3];
  const float* bq      = (const float*)d_in[4];
  const float* wk      = (const float*)d_in[5];
  const float* bk      = (const float*)d_in[6];
  const float* wv      = (const float*)d_in[7];
  const float* bvv     = (const float*)d_in[8];
  const float* wo      = (const float*)d_in[9];
  const float* bo      = (const float*)d_in[10];
  const float* w1      = (const float*)d_in[11];
  const float* b1      = (const float*)d_in[12];
  const float* w2      = (const float*)d_in[13];
  const float* b2      = (const float*)d_in[14];
  const float* ln1g    = (const float*)d_in[15];
  const float* ln1b    = (const float*)d_in[16];
  const float* ln2g    = (const float*)d_in[17];
  const float* ln2b    = (const float*)d_in[18];
  float* out = (float*)d_out;

  char* ws = (char*)d_ws;
  const size_t MB = 1024 * 1024;
  short* wqkvt = (short*)(ws + 0 * MB);    // 6MB
  short* wot   = (short*)(ws + 6 * MB);    // 2MB
  short* w1t   = (short*)(ws + 8 * MB);    // 8MB
  short* w2t   = (short*)(ws + 16 * MB);   // 8MB
  short* xb    = (short*)(ws + 24 * MB);   // 8MB (LN1 residual; dead after)
  short* qbuf  = (short*)(ws + 32 * MB);   // 8MB
  short* kbuf  = (short*)(ws + 40 * MB);   // 8MB
  short* vtb   = (short*)(ws + 48 * MB);   // 8MB  V^T [B][H][64][S]
  short* ctxb  = (short*)(ws + 56 * MB);   // 8MB
  short* pr0   = (short*)(ws + 64 * MB);   // 4 x 8MB proj partials; dead after LN1
  short* pr1   = (short*)(ws + 72 * MB);
  short* pr2   = (short*)(ws + 80 * MB);
  short* pr3   = (short*)(ws + 88 * MB);
  short* adnb  = (short*)(ws + 96 * MB);   // 8MB (FFN1 input AND LN2 residual)
  short* h1b   = (short*)(ws + 32 * MB);   // 32MB, reuses q/k/vt/ctx (dead after proj)
  short* hs0   = (short*)(ws + 64 * MB);   // FFN2 bf16 partials (overwrite pr0..3)
  short* hs1   = (short*)(ws + 72 * MB);
  short* hs2   = (short*)(ws + 80 * MB);
  short* hs3   = (short*)(ws + 88 * MB);
  float* lrow  = (float*)(ws + 104 * MB);  // 16KB
  float* bqkv  = (float*)(ws + 105 * MB);  // 12KB

  trans_all_kernel<<<12288, dim3(32, 8), 0, stream>>>(
      wq, wk, wv, wo, w1, w2, wqkvt, wot, w1t, w2t);
  concat_bias_kernel<<<12, 256, 0, stream>>>(bq, bk, bvv, bqkv);

  embed_kernel<<<4096, 256, 0, stream>>>(inputs, wte, xb);

  // fused QKV GEMM (256^2 kernel): -> q (pre-scaled), k row-major + v transposed
  gemm256_kernel<2, false, true><<<dim3(12, 16), 512, 0, stream>>>(
      xb, wqkvt, bqkv, nullptr, nullptr, nullptr, nullptr,
      qbuf, kbuf, vtb, MM, 3 * DD, DD, DD);

  attn_kernel<<<dim3(8, 16, 4), 256, 0, stream>>>(qbuf, kbuf, vtb, ctxb);

  // attention out-proj (128x256 kernel): split-K=4, bf16 partials; grid 512 = 2/CU
  gemmw_kernel<1, false, true><<<dim3(4, 32, 4), 512, 0, stream>>>(
      ctxb, wot, bo, pr0, pr1, pr2, pr3, MM, DD, DD, 256);

  // LN1: xb + pr0..3 -> adnb (bf16)
  ln_kernel<4, false, false><<<4096, 256, 0, stream>>>(
      pr0, pr1, pr2, pr3, xb, ln1g, ln1b, nullptr, adnb, nullptr, nullptr);

  // FFN1 (128x256 kernel): + fast GELU -> bf16; grid 512 = 2/CU
  gemmw_kernel<0, true, true><<<dim3(16, 32), 512, 0, stream>>>(
      adnb, w1t, b1, h1b, nullptr, nullptr, nullptr, MM, FF, DD, DD);

  // FFN2 (128x256 kernel): split-K=4, bf16 partials; grid 512 = 2/CU
  gemmw_kernel<1, false, true><<<dim3(4, 32, 4), 512, 0, stream>>>(
      h1b, w2t, b2, hs0, hs1, hs2, hs3, MM, DD, FF, 1024);

  // LN2: adnb residual + hs0..3 -> out (f32 logits) + fused CE row loss
  ln_kernel<4, true, true><<<4096, 256, 0, stream>>>(
      hs0, hs1, hs2, hs3, adnb, ln2g, ln2b, out, nullptr, targets, lrow);

  loss_reduce_kernel<<<1, 256, 0, stream>>>(lrow, out + (size_t)MM * DD);
}

// Round 19
// 218.407 us; speedup vs baseline: 1.0073x; 1.0073x over previous
//
#include <hip/hip_runtime.h>
#include <math.h>

// Problem constants
#define BB 4
#define SS 1024
#define DD 1024
#define HH 16
#define HDIM 64
#define FF 4096
#define MM 4096   // B*S

typedef short bf16x8 __attribute__((ext_vector_type(8)));
typedef short bf16x4 __attribute__((ext_vector_type(4)));
typedef float f32x4  __attribute__((ext_vector_type(4)));

static __device__ __forceinline__ short f2bf(float f){
  unsigned u = __float_as_uint(f);
  u += 0x7FFFu + ((u >> 16) & 1u);   // RNE
  return (short)(u >> 16);
}
static __device__ __forceinline__ float b2f(short s){
  return __uint_as_float(((unsigned)(unsigned short)s) << 16);
}

// fast erf (Abramowitz-Stegun 7.1.26, |abs err| <= 1.5e-7)
static __device__ __forceinline__ float erf_fast(float x){
  float ax = fabsf(x);
  float t  = __builtin_amdgcn_rcpf(1.0f + 0.3275911f * ax);
  float p  = t * (0.254829592f + t * (-0.284496736f + t * (1.421413741f +
             t * (-1.453152027f + t * 1.061405429f))));
  float e  = 1.0f - p * __expf(-ax * ax);
  return copysignf(e, x);
}

// async global->LDS, 16B per lane, LDS dest = base + lane*16 (wave-uniform base)
static __device__ __forceinline__ void gl_lds16(const short* g, short* l){
  __builtin_amdgcn_global_load_lds((const __attribute__((address_space(1))) unsigned int*)g,
                                   (__attribute__((address_space(3))) unsigned int*)l,
                                   16, 0, 0);
}

#define MFMA_BF16 __builtin_amdgcn_mfma_f32_16x16x32_bf16

// ------- merged weight f32 -> bf16 transpose (all 6 weights) + bias concat, 1 launch -------
__global__ __launch_bounds__(256) void trans_all_kernel(
    const float* __restrict__ wq, const float* __restrict__ wk,
    const float* __restrict__ wv, const float* __restrict__ wo,
    const float* __restrict__ w1, const float* __restrict__ w2,
    const float* __restrict__ bq, const float* __restrict__ bk,
    const float* __restrict__ bvv,
    short* __restrict__ wqkvt, short* __restrict__ wot,
    short* __restrict__ w1t,   short* __restrict__ w2t,
    float* __restrict__ bqkv){
  int idx = blockIdx.x;
  int tid5 = threadIdx.y * 32 + threadIdx.x;   // 0..255
  if (idx >= 12288){
    int t = (idx - 12288) * 256 + tid5;        // 0..3071
    float v = (t < 1024) ? bq[t] : (t < 2048 ? bk[t - 1024] : bvv[t - 2048]);
    bqkv[t] = v;
    return;
  }
  __shared__ float t[32][33];
  const float* src; short* dst; int R, C, cx, ry;
  if (idx < 4096){
    int wsel = idx >> 10, tt = idx & 1023;
    cx = tt & 31; ry = tt >> 5; R = 1024; C = 1024;
    src = (wsel == 0) ? wq : (wsel == 1) ? wk : (wsel == 2) ? wv : wo;
    dst = (wsel == 3) ? wot : wqkvt + (size_t)wsel * 1024 * 1024;
  } else if (idx < 8192){
    int tt = idx - 4096; cx = tt & 127; ry = tt >> 7; R = 1024; C = 4096;
    src = w1; dst = w1t;
  } else {
    int tt = idx - 8192; cx = tt & 31; ry = tt >> 5; R = 4096; C = 1024;
    src = w2; dst = w2t;
  }
  int c0 = cx * 32, r0 = ry * 32;
  int tx = threadIdx.x, ty = threadIdx.y;  // (32,8)
#pragma unroll
  for (int i = 0; i < 32; i += 8)
    t[ty + i][tx] = src[(size_t)(r0 + ty + i) * C + (c0 + tx)];
  __syncthreads();
#pragma unroll
  for (int i = 0; i < 32; i += 8)
    dst[(size_t)(c0 + ty + i) * R + (r0 + tx)] = f2bf(t[tx][ty + i]);
}

// ---------------- embedding + sinusoidal PE (bf16 out only) ----------------
__global__ __launch_bounds__(256) void embed_kernel(const int* __restrict__ inputs,
                                                    const float* __restrict__ wte,
                                                    short* __restrict__ xb){
  int idx4 = blockIdx.x * 256 + threadIdx.x;
  int row = idx4 >> 8;
  int d   = (idx4 & 255) * 4;
  int s   = row & (SS - 1);
  int tok = inputs[row];
  float4 w = *(const float4*)&wte[(size_t)tok * DD + d];
  const float cdiv = -9.210340371976184f / 512.0f;
  int i0 = d >> 1;
  float ang0 = (float)s * expf((float)i0 * cdiv);
  float ang1 = (float)s * expf((float)(i0 + 1) * cdiv);
  float x0 = w.x + sinf(ang0);
  float x1 = w.y + cosf(ang0);
  float x2 = w.z + sinf(ang1);
  float x3 = w.w + cosf(ang1);
  bf16x4 sb; sb[0]=f2bf(x0); sb[1]=f2bf(x1); sb[2]=f2bf(x2); sb[3]=f2bf(x3);
  *(bf16x4*)&xb[(size_t)row * DD + d] = sb;
}

// ---------------- 256x256 MFMA GEMM, 8 waves, BK=64, one-phase-ahead pipeline ----------------
// Round-14 configuration (measured best). Do not perturb.
template<int MODE, bool GELU, bool ADDBIAS>
__global__ __launch_bounds__(512, 2) void gemm256_kernel(const short* __restrict__ A,
    const short* __restrict__ Bt, const float* __restrict__ bias,
    short* __restrict__ o0, short* __restrict__ o1,
    short* __restrict__ o2, short* __restrict__ o3,
    short* __restrict__ qo, short* __restrict__ ko, short* __restrict__ vto,
    int M, int N, int K, int Kc){
  __shared__ __align__(16) short lds[8 * 8192];   // 128KB
  int tid = threadIdx.x;
  int lid = blockIdx.y * gridDim.x + blockIdx.x;
  int cpx = (gridDim.x * gridDim.y) >> 3;
  int swz = (lid & 7) * cpx + (lid >> 3);
  int n0 = (swz % gridDim.x) * 256;
  int m0 = (swz / gridDim.x) * 256;
  int bz = blockIdx.z;
  int kbeg = bz * Kc;
  int w = tid >> 6, lane = tid & 63, lr = lane & 15, lg = lane >> 4;
  int wm = w >> 2, wn = w & 3;          // 2 (M) x 4 (N) waves
  f32x4 acc[8][4] = {};

  int sr = lane >> 3;
  int sg = (lane & 7) ^ sr;
  auto STAGE_HALF = [&](int buf, int typ, int half, int kt){
    const short* s0 = (typ ? Bt : A) + (size_t)kbeg + sg * 8;
    int rb = (typ ? n0 : m0) + half * 128 + w * 8 + sr;
#pragma unroll
    for (int j = 0; j < 2; j++)
      gl_lds16(s0 + (size_t)(rb + j * 64) * K + kt * 64,
               &lds[(((buf << 2) | (typ << 1) | half) << 13) + (j << 12) + (w << 9)]);
  };

  int nt = Kc >> 6;   // >= 4 for all our shapes
  STAGE_HALF(0, 0, 0, 0); STAGE_HALF(0, 0, 1, 0);
  STAGE_HALF(0, 1, 0, 0); STAGE_HALF(0, 1, 1, 0);
  STAGE_HALF(1, 0, 0, 1); STAGE_HALF(1, 0, 1, 1);
  STAGE_HALF(1, 1, 0, 1); STAGE_HALF(1, 1, 1, 1);
  asm volatile("s_waitcnt vmcnt(8)" ::: "memory");   // tile0 landed; tile1 may fly
  __builtin_amdgcn_s_barrier();

  int lr64 = lr * 64;
  int ck0 = ((lg     ) ^ (lr & 7)) * 8;   // ks=0 swizzled chunk (shorts)
  int ck1 = ((lg + 4 ) ^ (lr & 7)) * 8;   // ks=1
  int brow = (wn & 1) << 12;              // (wn&1)*64 rows * 64 shorts/row

  bf16x8 Alo[4][2], Ahi[4][2], Blo[2][2], Bhi[2][2];

#define ABASE(b) ((((b) << 2) | wm) << 13) + lr64
#define BBASE(b) ((((b) << 2) | 2 | (wn >> 1)) << 13) + brow + lr64
#define RD_ALO(b) { int ab_ = ABASE(b); _Pragma("unroll") for (int fi_ = 0; fi_ < 4; fi_++){ \
    Alo[fi_][0] = *(const bf16x8*)&lds[ab_ + fi_ * 1024 + ck0]; \
    Alo[fi_][1] = *(const bf16x8*)&lds[ab_ + fi_ * 1024 + ck1]; } }
#define RD_AHI(b) { int ab_ = ABASE(b); _Pragma("unroll") for (int fi_ = 0; fi_ < 4; fi_++){ \
    Ahi[fi_][0] = *(const bf16x8*)&lds[ab_ + (fi_ + 4) * 1024 + ck0]; \
    Ahi[fi_][1] = *(const bf16x8*)&lds[ab_ + (fi_ + 4) * 1024 + ck1]; } }
#define RD_BLO(b) { int bb_ = BBASE(b); _Pragma("unroll") for (int ni_ = 0; ni_ < 2; ni_++){ \
    Blo[ni_][0] = *(const bf16x8*)&lds[bb_ + ni_ * 1024 + ck0]; \
    Blo[ni_][1] = *(const bf16x8*)&lds[bb_ + ni_ * 1024 + ck1]; } }
#define RD_BHI(b) { int bb_ = BBASE(b); _Pragma("unroll") for (int ni_ = 0; ni_ < 2; ni_++){ \
    Bhi[ni_][0] = *(const bf16x8*)&lds[bb_ + (ni_ + 2) * 1024 + ck0]; \
    Bhi[ni_][1] = *(const bf16x8*)&lds[bb_ + (ni_ + 2) * 1024 + ck1]; } }
#define QUAD(MB, NB, AF, BF) \
    __builtin_amdgcn_s_setprio(1); \
    _Pragma("unroll") for (int mi_ = 0; mi_ < 4; mi_++) \
      _Pragma("unroll") for (int ni_ = 0; ni_ < 2; ni_++){ \
        acc[mi_ + MB][ni_ + NB] = MFMA_BF16(AF[mi_][0], BF[ni_][0], acc[mi_ + MB][ni_ + NB], 0, 0, 0); \
        acc[mi_ + MB][ni_ + NB] = MFMA_BF16(AF[mi_][1], BF[ni_][1], acc[mi_ + MB][ni_ + NB], 0, 0, 0); } \
    __builtin_amdgcn_s_setprio(0);

  RD_ALO(0); RD_BLO(0);   // 12 reads in flight into tile0 frags

  for (int t = 0; t < nt; t++){
    int b = t & 1, bn = b ^ 1;
    RD_AHI(b);
    asm volatile("s_waitcnt lgkmcnt(8)" ::: "memory");
    __builtin_amdgcn_sched_barrier(0);
    QUAD(0, 0, Alo, Blo);
    __builtin_amdgcn_s_barrier();
    RD_BHI(b);
    if (t + 2 < nt){ STAGE_HALF(b, 0, 0, t + 2); STAGE_HALF(b, 0, 1, t + 2); }
    asm volatile("s_waitcnt lgkmcnt(4)" ::: "memory");
    __builtin_amdgcn_sched_barrier(0);
    QUAD(4, 0, Ahi, Blo);
    __builtin_amdgcn_s_barrier();
    if (t + 2 < nt) asm volatile("s_waitcnt vmcnt(4)" ::: "memory");
    else            asm volatile("s_waitcnt vmcnt(0)" ::: "memory");
    if (t + 2 < nt){ STAGE_HALF(b, 1, 0, t + 2); STAGE_HALF(b, 1, 1, t + 2); }
    asm volatile("s_waitcnt lgkmcnt(0)" ::: "memory");
    __builtin_amdgcn_sched_barrier(0);
    QUAD(4, 2, Ahi, Bhi);
    __builtin_amdgcn_s_barrier();
    QUAD(0, 2, Alo, Bhi);
    __builtin_amdgcn_sched_barrier(0);
    if (t + 1 < nt){ RD_ALO(bn); RD_BLO(bn); }
    __builtin_amdgcn_s_barrier();
  }
#undef QUAD
#undef RD_BHI
#undef RD_BLO
#undef RD_AHI
#undef RD_ALO
#undef BBASE
#undef ABASE

  short* slab = (MODE == 1) ? ((bz == 0) ? o0 : (bz == 1) ? o1 : (bz == 2) ? o2 : o3) : o0;
  bool addb = ADDBIAS && (MODE != 1 || bz == 0);
#pragma unroll
  for (int mi = 0; mi < 8; mi++){
#pragma unroll
    for (int ni = 0; ni < 4; ni++){
      int ng = n0 + wn * 64 + ni * 16 + lr;
      float bv = addb ? bias[ng] : 0.0f;
      int mg0 = m0 + wm * 128 + mi * 16 + 4 * lg;
      if (MODE == 2){
        int sel = n0 >> 10;
        if (sel == 2){
          int d = ng & 1023; int hh = d >> 6, nn = d & 63;
          int bI = mg0 >> 10, sI = mg0 & 1023;
          bf16x4 pk;
#pragma unroll
          for (int r = 0; r < 4; r++) pk[r] = f2bf(acc[mi][ni][r] + bv);
          *(bf16x4*)&vto[(((size_t)(bI * HH + hh)) * HDIM + nn) * SS + sI] = pk;
        } else {
          short* dst = (sel == 0) ? qo : ko;
          float qscl = (sel == 0) ? 0.125f : 1.0f;   // fold 1/sqrt(HDIM) into Q
#pragma unroll
          for (int r = 0; r < 4; r++)
            dst[(size_t)(mg0 + r) * DD + (ng & 1023)] = f2bf((acc[mi][ni][r] + bv) * qscl);
        }
      } else {
#pragma unroll
        for (int r = 0; r < 4; r++){
          float v = acc[mi][ni][r] + bv;
          if (GELU) v = 0.5f * v * (1.0f + erf_fast(v * 0.70710678118654752f));
          slab[(size_t)(mg0 + r) * N + ng] = f2bf(v);
        }
      }
    }
  }
}

// ---------------- causal flash attention v5 (round-14 version, unchanged) ----------------
__global__ __launch_bounds__(256) void attn_kernel(const short* __restrict__ qb,
                                                   const short* __restrict__ kb,
                                                   const short* __restrict__ vtb,
                                                   short* __restrict__ ctxb){
  __shared__ __align__(16) short k_lds[2][64 * 64];
  __shared__ __align__(16) short v_lds[2][64 * 64];
  __shared__ __align__(16) short p_lds[4][2][16 * 72];
  int qp = blockIdx.x, h = blockIdx.y, b = blockIdx.z;
  int Tlo = qp, Thi = 15 - qp;
  int tid = threadIdx.x, w = tid >> 6, lane = tid & 63, lr = lane & 15, lg = lane >> 4;

  const short* kp0 = kb  + (size_t)b * SS * DD + h * HDIM;
  const short* vt0 = vtb + (size_t)(b * HH + h) * HDIM * SS;

  bf16x8 qf0[2], qf1[2];
#pragma unroll
  for (int ti = 0; ti < 2; ti++){
    int T = ti ? Thi : Tlo;
    const short* qp_ = qb + ((size_t)(b * SS + T * 64 + w * 16 + lr) * DD + h * HDIM);
    qf0[ti] = *(const bf16x8*)&qp_[lg * 8];
    qf1[ti] = *(const bf16x8*)&qp_[32 + lg * 8];
  }

  bf16x8 ones;
#pragma unroll
  for (int j = 0; j < 8; j++) ones[j] = (short)0x3F80;

  float m[2][4], l[2][4];
  f32x4 acc[2][4] = {};
#pragma unroll
  for (int ti = 0; ti < 2; ti++)
#pragma unroll
    for (int r = 0; r < 4; r++){ m[ti][r] = -1e30f; l[ti][r] = 0.0f; }

  int srow8 = lane >> 3;
  int sjs   = (lane & 7) ^ srow8;
  auto STAGE = [&](int buf, int kt){
#pragma unroll
    for (int i = 0; i < 2; i++){
      int rb  = (w + 4 * i) * 8;
      int row = rb + srow8;
      gl_lds16(kp0 + (size_t)(kt * 64 + row) * DD + sjs * 8, &k_lds[buf][rb * 64]);
      gl_lds16(vt0 + (size_t)row * SS + kt * 64 + sjs * 8,   &v_lds[buf][rb * 64]);
    }
  };

  int cur = 0;
  STAGE(0, 0);
  asm volatile("s_waitcnt vmcnt(0)" ::: "memory");
  __syncthreads();

  bf16x8 pf0[2], pf1[2];
  for (int kt = 0; kt <= Thi; kt++){
    if (kt < Thi) STAGE(cur ^ 1, kt + 1);

    bf16x8 kf0[4], kf1[4];
#pragma unroll
    for (int sub = 0; sub < 4; sub++){
      int r = sub * 16 + lr;
      kf0[sub] = *(const bf16x8*)&k_lds[cur][r * 64 + ((lg     ^ (r & 7)) * 8)];
      kf1[sub] = *(const bf16x8*)&k_lds[cur][r * 64 + (((lg+4) ^ (r & 7)) * 8)];
    }

#pragma unroll
    for (int ti = 0; ti < 2; ti++){
      int T = ti ? Thi : Tlo;
      if (kt > T) continue;
      f32x4 sc4[4];
      __builtin_amdgcn_s_setprio(1);
#pragma unroll
      for (int sub = 0; sub < 4; sub++){
        f32x4 t = {};
        t = MFMA_BF16(qf0[ti], kf0[sub], t, 0, 0, 0);
        t = MFMA_BF16(qf1[ti], kf1[sub], t, 0, 0, 0);
        sc4[sub] = t;
      }
      __builtin_amdgcn_s_setprio(0);
      if (kt == T){
#pragma unroll
        for (int sub = 0; sub < 4; sub++)
#pragma unroll
          for (int r = 0; r < 4; r++)
            if (16 * sub + lr > 16 * w + 4 * lg + r) sc4[sub][r] = -1e30f;
      }

      float pm[4];
#pragma unroll
      for (int r = 0; r < 4; r++)
        pm[r] = fmaxf(fmaxf(sc4[0][r], sc4[1][r]), fmaxf(sc4[2][r], sc4[3][r]));
#pragma unroll
      for (int off = 1; off < 16; off <<= 1)
#pragma unroll
        for (int r = 0; r < 4; r++) pm[r] = fmaxf(pm[r], __shfl_xor(pm[r], off));

      float dmax = fmaxf(fmaxf(pm[0] - m[ti][0], pm[1] - m[ti][1]),
                         fmaxf(pm[2] - m[ti][2], pm[3] - m[ti][3]));
      if (!__all(dmax <= 8.0f)){
        float scl[4];
#pragma unroll
        for (int r = 0; r < 4; r++){
          float mn = fmaxf(m[ti][r], pm[r]);
          scl[r] = __expf(m[ti][r] - mn);
          m[ti][r] = mn;
          l[ti][r] *= scl[r];
        }
#pragma unroll
        for (int nb = 0; nb < 4; nb++)
#pragma unroll
          for (int r = 0; r < 4; r++) acc[ti][nb][r] *= scl[r];
      }

      short* pw = &p_lds[w][ti][0];
#pragma unroll
      for (int sub = 0; sub < 4; sub++)
#pragma unroll
        for (int r = 0; r < 4; r++)
          pw[(4 * lg + r) * 72 + sub * 16 + lr] = f2bf(__expf(sc4[sub][r] - m[ti][r]));
      pf0[ti] = *(const bf16x8*)&pw[lr * 72 + lg * 8];
      pf1[ti] = *(const bf16x8*)&pw[lr * 72 + 32 + lg * 8];
    }

    bf16x8 vf0[4], vf1[4];
#pragma unroll
    for (int nb = 0; nb < 4; nb++){
      int r = nb * 16 + lr;
      vf0[nb] = *(const bf16x8*)&v_lds[cur][r * 64 + ((lg     ^ (r & 7)) * 8)];
      vf1[nb] = *(const bf16x8*)&v_lds[cur][r * 64 + (((lg+4) ^ (r & 7)) * 8)];
    }

#pragma unroll
    for (int ti = 0; ti < 2; ti++){
      int T = ti ? Thi : Tlo;
      if (kt > T) continue;
      f32x4 rsum = {};
      __builtin_amdgcn_s_setprio(1);
      rsum = MFMA_BF16(pf0[ti], ones, rsum, 0, 0, 0);
      rsum = MFMA_BF16(pf1[ti], ones, rsum, 0, 0, 0);
#pragma unroll
      for (int nb = 0; nb < 4; nb++){
        acc[ti][nb] = MFMA_BF16(pf0[ti], vf0[nb], acc[ti][nb], 0, 0, 0);
        acc[ti][nb] = MFMA_BF16(pf1[ti], vf1[nb], acc[ti][nb], 0, 0, 0);
      }
      __builtin_amdgcn_s_setprio(0);
#pragma unroll
      for (int r = 0; r < 4; r++) l[ti][r] += rsum[r];
    }

    asm volatile("s_waitcnt vmcnt(0)" ::: "memory");
    __syncthreads();
    cur ^= 1;
  }

#pragma unroll
  for (int ti = 0; ti < 2; ti++){
    int T = ti ? Thi : Tlo;
#pragma unroll
    for (int r = 0; r < 4; r++){
      float inv = 1.0f / l[ti][r];
      int row = T * 64 + w * 16 + 4 * lg + r;
#pragma unroll
      for (int nb = 0; nb < 4; nb++)
        ctxb[(size_t)(b * SS + row) * DD + h * HDIM + nb * 16 + lr] = f2bf(acc[ti][nb][r] * inv);
    }
  }
}

// ---------------- LayerNorm( bf16 residual + sum of NPART bf16 partial slabs ) ----------------
template<int NPART, bool WF32, bool LOSS>
__global__ __launch_bounds__(256) void ln_kernel(const short* __restrict__ p0,
                                                 const short* __restrict__ p1,
                                                 const short* __restrict__ p2,
                                                 const short* __restrict__ p3,
                                                 const short* __restrict__ resb,
                                                 const float* __restrict__ g,
                                                 const float* __restrict__ be,
                                                 float* __restrict__ of,
                                                 short* __restrict__ ob,
                                                 const int* __restrict__ tgt,
                                                 float* __restrict__ lrow){
  int row = blockIdx.x, tid = threadIdx.x;
  size_t base = (size_t)row * DD + tid * 4;
  bf16x4 rv = *(const bf16x4*)&resb[base];
  float x0 = b2f(rv[0]), x1 = b2f(rv[1]), x2 = b2f(rv[2]), x3 = b2f(rv[3]);
  const short* ps[4] = {p0, p1, p2, p3};
#pragma unroll
  for (int p = 0; p < NPART; p++){
    bf16x4 pv = *(const bf16x4*)&ps[p][base];
    x0 += b2f(pv[0]); x1 += b2f(pv[1]); x2 += b2f(pv[2]); x3 += b2f(pv[3]);
  }
  float s = x0 + x1 + x2 + x3;
  float q = x0 * x0 + x1 * x1 + x2 * x2 + x3 * x3;
#pragma unroll
  for (int off = 32; off; off >>= 1){ s += __shfl_xor(s, off); q += __shfl_xor(q, off); }
  __shared__ float red[9];
  if ((tid & 63) == 0){ red[tid >> 6] = s; red[4 + (tid >> 6)] = q; }
  __syncthreads();
  s = red[0] + red[1] + red[2] + red[3];
  q = red[4] + red[5] + red[6] + red[7];
  float mean = s * (1.0f / DD);
  float var  = q * (1.0f / DD) - mean * mean;
  float rstd = rsqrtf(var + 1e-5f);
  float4 gv  = *(const float4*)&g[tid * 4];
  float4 bev = *(const float4*)&be[tid * 4];
  float y0 = (x0 - mean) * rstd * gv.x + bev.x;
  float y1 = (x1 - mean) * rstd * gv.y + bev.y;
  float y2 = (x2 - mean) * rstd * gv.z + bev.z;
  float y3 = (x3 - mean) * rstd * gv.w + bev.w;
  if (WF32){
    *(float4*)&of[base] = make_float4(y0, y1, y2, y3);
  } else {
    bf16x4 sb; sb[0]=f2bf(y0); sb[1]=f2bf(y1); sb[2]=f2bf(y2); sb[3]=f2bf(y3);
    *(bf16x4*)&ob[base] = sb;
  }
  if (LOSS){
    __syncthreads();
    float mx = fmaxf(fmaxf(y0, y1), fmaxf(y2, y3));
#pragma unroll
    for (int off = 32; off; off >>= 1) mx = fmaxf(mx, __shfl_xor(mx, off));
    if ((tid & 63) == 0) red[tid >> 6] = mx;
    int t = tgt[row];
    if (tid == (t >> 2))
      red[8] = ((t & 3) == 0) ? y0 : ((t & 3) == 1) ? y1 : ((t & 3) == 2) ? y2 : y3;
    __syncthreads();
    mx = fmaxf(fmaxf(red[0], red[1]), fmaxf(red[2], red[3]));
    float se = __expf(y0 - mx) + __expf(y1 - mx) + __expf(y2 - mx) + __expf(y3 - mx);
#pragma unroll
    for (int off = 32; off; off >>= 1) se += __shfl_xor(se, off);
    if ((tid & 63) == 0) red[4 + (tid >> 6)] = se;
    __syncthreads();
    if (tid == 0){
      float tot = red[4] + red[5] + red[6] + red[7];
      lrow[row] = mx + logf(tot) - red[8];
    }
  }
}

__global__ __launch_bounds__(256) void loss_reduce_kernel(const float* __restrict__ pr,
                                                          float* __restrict__ outp){
  int tid = threadIdx.x;
  float s = 0.0f;
  for (int i = tid; i < MM; i += 256) s += pr[i];
#pragma unroll
  for (int off = 32; off; off >>= 1) s += __shfl_xor(s, off);
  __shared__ float red[4];
  if ((tid & 63) == 0) red[tid >> 6] = s;
  __syncthreads();
  if (tid == 0) outp[0] = (red[0] + red[1] + red[2] + red[3]) * (1.0f / MM);
}

// ---------------- launch ----------------
extern "C" void kernel_launch(void* const* d_in, const int* in_sizes, int n_in,
                              void* d_out, int out_size, void* d_ws, size_t ws_size,
                              hipStream_t stream){
  const int*   inputs  = (const int*)  d_in[0];
  const int*   targets = (const int*)  d_in[1];
  const float* wte     = (const float*)d_in[2];
  const float* wq      = (const float*)d_in[3];
  const float* bq      = (const float*)d_in[4];
  const float* wk      = (const float*)d_in[5];
  const float* bk      = (const float*)d_in[6];
  const float* wv      = (const float*)d_in[7];
  const float* bvv     = (const float*)d_in[8];
  const float* wo      = (const float*)d_in[9];
  const float* bo      = (const float*)d_in[10];
  const float* w1      = (const float*)d_in[11];
  const float* b1      = (const float*)d_in[12];
  const float* w2      = (const float*)d_in[13];
  const float* b2      = (const float*)d_in[14];
  const float* ln1g    = (const float*)d_in[15];
  const float* ln1b    = (const float*)d_in[16];
  const float* ln2g    = (const float*)d_in[17];
  const float* ln2b    = (const float*)d_in[18];
  float* out = (float*)d_out;

  char* ws = (char*)d_ws;
  const size_t MB = 1024 * 1024;
  short* wqkvt = (short*)(ws + 0 * MB);    // 6MB
  short* wot   = (short*)(ws + 6 * MB);    // 2MB
  short* w1t   = (short*)(ws + 8 * MB);    // 8MB
  short* w2t   = (short*)(ws + 16 * MB);   // 8MB
  short* xb    = (short*)(ws + 24 * MB);   // 8MB (LN1 residual; dead after)
  short* qbuf  = (short*)(ws + 32 * MB);   // 8MB
  short* kbuf  = (short*)(ws + 40 * MB);   // 8MB
  short* vtb   = (short*)(ws + 48 * MB);   // 8MB  V^T [B][H][64][S]
  short* ctxb  = (short*)(ws + 56 * MB);   // 8MB
  short* pr0   = (short*)(ws + 64 * MB);   // 4 x 8MB proj partials; dead after LN1
  short* pr1   = (short*)(ws + 72 * MB);
  short* pr2   = (short*)(ws + 80 * MB);
  short* pr3   = (short*)(ws + 88 * MB);
  short* adnb  = (short*)(ws + 96 * MB);   // 8MB (FFN1 input AND LN2 residual)
  short* h1b   = (short*)(ws + 32 * MB);   // 32MB, reuses q/k/vt/ctx (dead after proj)
  short* hs0   = (short*)(ws + 64 * MB);   // FFN2 bf16 partials (overwrite pr0..3)
  short* hs1   = (short*)(ws + 72 * MB);
  short* hs2   = (short*)(ws + 80 * MB);
  short* hs3   = (short*)(ws + 88 * MB);
  float* lrow  = (float*)(ws + 104 * MB);  // 16KB
  float* bqkv  = (float*)(ws + 105 * MB);  // 12KB

  // weights transpose + bias concat, one launch
  trans_all_kernel<<<12300, dim3(32, 8), 0, stream>>>(
      wq, wk, wv, wo, w1, w2, bq, bk, bvv, wqkvt, wot, w1t, w2t, bqkv);

  embed_kernel<<<4096, 256, 0, stream>>>(inputs, wte, xb);

  // fused QKV GEMM: -> q (pre-scaled), k row-major + v transposed
  gemm256_kernel<2, false, true><<<dim3(12, 16), 512, 0, stream>>>(
      xb, wqkvt, bqkv, nullptr, nullptr, nullptr, nullptr,
      qbuf, kbuf, vtb, MM, 3 * DD, DD, DD);

  attn_kernel<<<dim3(8, 16, 4), 256, 0, stream>>>(qbuf, kbuf, vtb, ctxb);

  // attention out-proj: split-K=4, bf16 partials
  gemm256_kernel<1, false, true><<<dim3(4, 16, 4), 512, 0, stream>>>(
      ctxb, wot, bo, pr0, pr1, pr2, pr3,
      nullptr, nullptr, nullptr, MM, DD, DD, 256);

  // LN1: xb + pr0..3 -> adnb (bf16)
  ln_kernel<4, false, false><<<4096, 256, 0, stream>>>(
      pr0, pr1, pr2, pr3, xb, ln1g, ln1b, nullptr, adnb, nullptr, nullptr);

  // FFN1: + fast GELU -> bf16
  gemm256_kernel<0, true, true><<<dim3(16, 16), 512, 0, stream>>>(
      adnb, w1t, b1, h1b, nullptr, nullptr, nullptr,
      nullptr, nullptr, nullptr, MM, FF, DD, DD);

  // FFN2: split-K=4, bf16 partials
  gemm256_kernel<1, false, true><<<dim3(4, 16, 4), 512, 0, stream>>>(
      h1b, w2t, b2, hs0, hs1, hs2, hs3,
      nullptr, nullptr, nullptr, MM, DD, FF, 1024);

  // LN2: adnb residual + hs0..3 -> out (f32 logits) + fused CE row loss
  ln_kernel<4, true, true><<<4096, 256, 0, stream>>>(
      hs0, hs1, hs2, hs3, adnb, ln2g, ln2b, out, nullptr, targets, lrow);

  loss_reduce_kernel<<<1, 256, 0, stream>>>(lrow, out + (size_t)MM * DD);
}